// Round 1
// baseline (104.603 us; speedup 1.0000x reference)
//
#include <hip/hip_runtime.h>

// ChebGraphConv: out[b,t,n,o] = sum_k diag(Tks[k])[n] * (x[b,t,n,:] @ Theta[k])[o] + sum_k bias[k,o]
// Restructured: W_n[c,o] = sum_k d[k,n]*Theta[k][c,o]  (built per-block in LDS as bf16),
// then per-node GEMM X_n(768x64) @ W_n(64x64) via mfma_f32_16x16x32_bf16.
// B=32,T=24 -> BT=768 rows per node. N=1024, C_IN=C_OUT=64, K=3.

#define NNODES 1024
#define CIN    64
#define COUT   64

typedef __attribute__((ext_vector_type(8))) short  short8;  // 8 x bf16 (4 VGPRs) MFMA A/B frag
typedef __attribute__((ext_vector_type(4))) float  f32x4;   // MFMA C/D frag

// round-to-nearest-even f32 -> bf16 bits
__device__ __forceinline__ unsigned short f2bf(float f) {
    union { float f; unsigned u; } v; v.f = f;
    unsigned r = v.u + 0x7FFFu + ((v.u >> 16) & 1u);
    return (unsigned short)(r >> 16);
}

__global__ __launch_bounds__(256) void cheb_fused(
    const float* __restrict__ x,      // [768*1024*64] viewed flat: ((bt)*1024 + n)*64 + c
    const float* __restrict__ Tks,    // [3*1024*1024]
    const float* __restrict__ Theta,  // [3*64*64]  k*4096 + c*64 + o
    const float* __restrict__ bias,   // [3*64]
    float* __restrict__ out)          // [768*1024*64]
{
    // W^T in LDS: WT[o][c], padded row stride 72 (144B) so b128 frag reads are 2-way-bank (free)
    __shared__ __align__(16) unsigned short WT[COUT][72];
    __shared__ float bsum[COUT];

    const int blk  = blockIdx.x;
    const int n    = blk >> 1;   // node id
    const int half = blk & 1;    // which half of the 768 bt-rows
    const int tid  = threadIdx.x;

    // diag(T_k)[n]
    const float d0 = Tks[(size_t)0 * NNODES * NNODES + (size_t)n * NNODES + n];
    const float d1 = Tks[(size_t)1 * NNODES * NNODES + (size_t)n * NNODES + n];
    const float d2 = Tks[(size_t)2 * NNODES * NNODES + (size_t)n * NNODES + n];

    // Build WT[o][c] = sum_k d_k * Theta[k][c][o]  (Theta reads coalesced over o)
    for (int idx = tid; idx < CIN * COUT; idx += 256) {
        const int c = idx >> 6;
        const int o = idx & 63;
        const float w = d0 * Theta[c * 64 + o]
                      + d1 * Theta[4096 + c * 64 + o]
                      + d2 * Theta[8192 + c * 64 + o];
        WT[o][c] = f2bf(w);
    }
    if (tid < COUT) bsum[tid] = bias[tid] + bias[64 + tid] + bias[128 + tid];
    __syncthreads();

    const int wave = tid >> 6;
    const int lane = tid & 63;
    const int lrow = lane & 15;  // A-frag row / B-frag col / D col
    const int lgrp = lane >> 4;  // k-group (and D row-group)

    // Hoist the 8 B-fragments (4 col-tiles x 2 K-halves) — constant for the whole block.
    // B-frag lane layout: col = lane&15, k = (lane>>4)*8 + j  -> contiguous 16B in WT row.
    short8 bfrag[4][2];
    #pragma unroll
    for (int nb = 0; nb < 4; ++nb) {
        #pragma unroll
        for (int kk = 0; kk < 2; ++kk) {
            const unsigned short* p = &WT[nb * 16 + lrow][kk * 32 + lgrp * 8];
            bfrag[nb][kk] = *reinterpret_cast<const short8*>(p);
        }
    }
    float bs[4];
    #pragma unroll
    for (int nb = 0; nb < 4; ++nb) bs[nb] = bsum[nb * 16 + lrow];

    // Each wave: 96 rows = 6 iterations of a 16x64 output tile.
    const int btbase = half * 384 + wave * 96;

    for (int it = 0; it < 6; ++it) {
        // ---- load A tile: 16 rows x 64 c (f32), per-lane 16 floats ----
        const int bt = btbase + it * 16 + lrow;
        const float* xrow = x + ((size_t)bt * NNODES + n) * CIN;
        // A-frag: row = lane&15, k = (lane>>4)*8 + j ; K-half kk adds 32
        const f32x4 xa0 = *reinterpret_cast<const f32x4*>(xrow + lgrp * 8);
        const f32x4 xa1 = *reinterpret_cast<const f32x4*>(xrow + lgrp * 8 + 4);
        const f32x4 xb0 = *reinterpret_cast<const f32x4*>(xrow + 32 + lgrp * 8);
        const f32x4 xb1 = *reinterpret_cast<const f32x4*>(xrow + 32 + lgrp * 8 + 4);

        short8 a0, a1;
        #pragma unroll
        for (int j = 0; j < 4; ++j) {
            a0[j]     = (short)f2bf(xa0[j]);
            a0[4 + j] = (short)f2bf(xa1[j]);
            a1[j]     = (short)f2bf(xb0[j]);
            a1[4 + j] = (short)f2bf(xb1[j]);
        }

        // ---- 8 MFMAs: 4 col-tiles x 2 K-halves ----
        f32x4 acc[4] = {f32x4{0,0,0,0}, f32x4{0,0,0,0}, f32x4{0,0,0,0}, f32x4{0,0,0,0}};
        #pragma unroll
        for (int nb = 0; nb < 4; ++nb) {
            acc[nb] = __builtin_amdgcn_mfma_f32_16x16x32_bf16(a0, bfrag[nb][0], acc[nb], 0, 0, 0);
            acc[nb] = __builtin_amdgcn_mfma_f32_16x16x32_bf16(a1, bfrag[nb][1], acc[nb], 0, 0, 0);
        }

        // ---- epilogue: D layout col = lane&15, row = (lane>>4)*4 + j ----
        const int btr = btbase + it * 16 + lgrp * 4;
        #pragma unroll
        for (int nb = 0; nb < 4; ++nb) {
            const size_t obase = ((size_t)btr * NNODES + n) * COUT + nb * 16 + lrow;
            const float bv = bs[nb];
            #pragma unroll
            for (int j = 0; j < 4; ++j) {
                out[obase + (size_t)j * NNODES * COUT] = acc[nb][j] + bv;
            }
        }
    }
}

extern "C" void kernel_launch(void* const* d_in, const int* in_sizes, int n_in,
                              void* d_out, int out_size, void* d_ws, size_t ws_size,
                              hipStream_t stream) {
    const float* x     = (const float*)d_in[0];
    const float* Tks   = (const float*)d_in[1];
    const float* Theta = (const float*)d_in[2];
    const float* bias  = (const float*)d_in[3];
    float* out = (float*)d_out;

    dim3 grid(NNODES * 2);   // 2 blocks per node (bt split in halves of 384)
    dim3 block(256);
    hipLaunchKernelGGL(cheb_fused, grid, block, 0, stream, x, Tks, Theta, bias, out);
}

// Round 2
// 92.352 us; speedup vs baseline: 1.1327x; 1.1327x over previous
//
#include <hip/hip_runtime.h>

// ChebGraphConv restructured as ONE flat GEMM with K=192:
//   out[r][o] = sum_{k,c} (d_k[n(r)] * x[r][c]) * Theta[k][c][o] + sum_k bias[k][o]
// where r = bt*1024 + n is the flat row index (contiguous in memory!),
// d_k[n] = diag(Tks[k])[n].  A-rows are consecutive 256B rows -> coalesced.
// B' (3 x 64 x 64) is global-constant, staged once per block in LDS as bf16.
// B=32,T=24,N=1024 -> 786432 rows.  C_IN=C_OUT=64, K(cheb)=3.

#define NNODES 1024
#define ROWS_PER_BLOCK 256
#define NBLOCKS 3072          // 786432 / 256
#define ITERS 4               // 256 rows / (4 waves * 16 rows)

typedef __attribute__((ext_vector_type(8))) short  short8;  // 8 x bf16 MFMA A/B frag
typedef __attribute__((ext_vector_type(4))) float  f32x4;   // MFMA C/D frag

// round-to-nearest-even f32 -> bf16 bits
__device__ __forceinline__ unsigned short f2bf(float f) {
    union { float f; unsigned u; } v; v.f = f;
    unsigned r = v.u + 0x7FFFu + ((v.u >> 16) & 1u);
    return (unsigned short)(r >> 16);
}

__global__ __launch_bounds__(256, 4) void cheb_flat(
    const float* __restrict__ x,      // [786432 * 64]
    const float* __restrict__ Tks,    // [3 * 1024 * 1024]
    const float* __restrict__ Theta,  // [3 * 64 * 64]  k*4096 + c*64 + o
    const float* __restrict__ bias,   // [3 * 64]
    float* __restrict__ out)          // [786432 * 64]
{
    // WT[k][o][c] = bf16(Theta[k][c][o]); pad stride 72 -> b128 frag reads conflict-free
    __shared__ __align__(16) unsigned short WT[3][64][72];
    __shared__ __align__(16) float d4[ROWS_PER_BLOCK][4];   // {d0,d1,d2,0} per local row
    __shared__ float bsum[64];

    const int tid = threadIdx.x;
    const int rowbase = blockIdx.x * ROWS_PER_BLOCK;

    // ---- stage B' (transpose Theta into LDS as bf16), vectorized over o ----
    for (int idx = tid; idx < 3 * 64 * 16; idx += 256) {
        const int k   = idx >> 10;          // 64*16 = 1024 per k
        const int rem = idx & 1023;
        const int c   = rem >> 4;
        const int og  = (rem & 15) << 2;    // o-group of 4
        const f32x4 th = *reinterpret_cast<const f32x4*>(Theta + k * 4096 + c * 64 + og);
        WT[k][og + 0][c] = f2bf(th[0]);
        WT[k][og + 1][c] = f2bf(th[1]);
        WT[k][og + 2][c] = f2bf(th[2]);
        WT[k][og + 3][c] = f2bf(th[3]);
    }
    // ---- stage diag scales for this block's rows ----
    for (int r = tid; r < ROWS_PER_BLOCK; r += 256) {
        const int n = (rowbase + r) & (NNODES - 1);
        const size_t diag = (size_t)n * (NNODES + 1);
        f32x4 v;
        v[0] = Tks[diag];
        v[1] = Tks[(size_t)NNODES * NNODES + diag];
        v[2] = Tks[(size_t)2 * NNODES * NNODES + diag];
        v[3] = 0.0f;
        *reinterpret_cast<f32x4*>(&d4[r][0]) = v;
    }
    if (tid < 64) bsum[tid] = bias[tid] + bias[64 + tid] + bias[128 + tid];
    __syncthreads();

    const int wave = tid >> 6;
    const int lane = tid & 63;
    const int lrow = lane & 15;   // A row / B col(o) / D col
    const int lgrp = lane >> 4;   // k-subgroup / D row-group

    float bs[4];
    #pragma unroll
    for (int nb = 0; nb < 4; ++nb) bs[nb] = bsum[nb * 16 + lrow];

    #pragma unroll 1
    for (int it = 0; it < ITERS; ++it) {
        const int lr  = it * 64 + wave * 16 + lrow;  // local row for A-frag
        const float* xrow = x + (size_t)(rowbase + lr) * 64;

        // A-row floats: c = lgrp*8 + j (+4) for half 0; 32 + lgrp*8 + j (+4) for half 1
        const f32x4 x0 = *reinterpret_cast<const f32x4*>(xrow + lgrp * 8);
        const f32x4 x1 = *reinterpret_cast<const f32x4*>(xrow + lgrp * 8 + 4);
        const f32x4 x2 = *reinterpret_cast<const f32x4*>(xrow + 32 + lgrp * 8);
        const f32x4 x3 = *reinterpret_cast<const f32x4*>(xrow + 32 + lgrp * 8 + 4);

        const f32x4 dv = *reinterpret_cast<const f32x4*>(&d4[lr][0]);

        // build 6 A-frags: m = k*2 + h; element j -> d_k * x[h*32 + lgrp*8 + j]
        short8 af[6];
        #pragma unroll
        for (int k = 0; k < 3; ++k) {
            const float dk = dv[k];
            #pragma unroll
            for (int j = 0; j < 4; ++j) {
                af[k * 2    ][j]     = (short)f2bf(dk * x0[j]);
                af[k * 2    ][4 + j] = (short)f2bf(dk * x1[j]);
                af[k * 2 + 1][j]     = (short)f2bf(dk * x2[j]);
                af[k * 2 + 1][4 + j] = (short)f2bf(dk * x3[j]);
            }
        }

        f32x4 acc[4] = {f32x4{0,0,0,0}, f32x4{0,0,0,0}, f32x4{0,0,0,0}, f32x4{0,0,0,0}};
        #pragma unroll
        for (int k = 0; k < 3; ++k) {
            #pragma unroll
            for (int h = 0; h < 2; ++h) {
                #pragma unroll
                for (int nb = 0; nb < 4; ++nb) {
                    const unsigned short* bp = &WT[k][nb * 16 + lrow][h * 32 + lgrp * 8];
                    const short8 bf = *reinterpret_cast<const short8*>(bp);
                    acc[nb] = __builtin_amdgcn_mfma_f32_16x16x32_bf16(af[k * 2 + h], bf, acc[nb], 0, 0, 0);
                }
            }
        }

        // D layout: col = lane&15, row = lgrp*4 + j  -> 64B full-line segments per store
        const int orow = rowbase + it * 64 + wave * 16 + lgrp * 4;
        #pragma unroll
        for (int nb = 0; nb < 4; ++nb) {
            const float bv = bs[nb];
            const size_t obase = (size_t)orow * 64 + nb * 16 + lrow;
            #pragma unroll
            for (int j = 0; j < 4; ++j) {
                out[obase + (size_t)j * 64] = acc[nb][j] + bv;
            }
        }
        __syncthreads();  // keeps B-frags in LDS (blocks LICM reg-hoist), waves stay in step
    }
}

extern "C" void kernel_launch(void* const* d_in, const int* in_sizes, int n_in,
                              void* d_out, int out_size, void* d_ws, size_t ws_size,
                              hipStream_t stream) {
    const float* x     = (const float*)d_in[0];
    const float* Tks   = (const float*)d_in[1];
    const float* Theta = (const float*)d_in[2];
    const float* bias  = (const float*)d_in[3];
    float* out = (float*)d_out;

    hipLaunchKernelGGL(cheb_flat, dim3(NBLOCKS), dim3(256), 0, stream,
                       x, Tks, Theta, bias, out);
}